// Round 5
// baseline (134.661 us; speedup 1.0000x reference)
//
#include <hip/hip_runtime.h>

// Problem constants: v (targets y), v_pred (queries x) are [4, 8192, 3] fp32.
#define BB 4
#define NN 8192
#define MM 8192
#define BN (BB * NN)

#define BLK 256        // threads per block = 4 waves
#define QB  256        // queries per block = 8 A-tiles of 32 (2 per wave)
#define TC  1024       // targets per s-chunk = 32 B-tiles (32 KB LDS image)
#define S   (MM / TC)  // 8 s-chunks = 8 blocks per (ib,b) group
#define NJT (TC / 32)  // 32 j-tiles per chunk
#define NGRP ((NN / QB) * BB)   // 128 groups
// grid (NN/QB, S, BB) = (32, 8, 4) = 1024 blocks = 4 blocks/CU, 16 waves/CU.

typedef __bf16 bf16x8 __attribute__((ext_vector_type(8)));
typedef float  f32x16 __attribute__((ext_vector_type(16)));

// ws layout (bytes):
//   [0, 1MB)       part: per-query per-s minima, float[128 groups][8 s][256 q]
//   [1MB, +512)    group_cnt[128] (poisoned; base probed)
//   +512           total (float, poisoned; bias subtracted exactly)
//   +516           gcnt (int, poisoned; base probed)
//   +520           probe (int, NEVER written -> holds the fill pattern)
// Counter trick: ws arrives uniformly filled (one fillBufferAligned over the
// whole ws). Counters start at unknown-but-uniform P; we read P from the probe
// word, so last-block detection (old == P + count - 1) is poison-value-agnostic.
// If an iteration ever skips re-poison, finalize simply doesn't re-fire and
// out[] keeps the (identical, deterministic) previous value — still correct.

// v_mfma_f32_32x32x16_bf16 (layouts verified by R0/R2 absmax=0.0):
//   A: row=lane&31, k=(lane>>5)*8+e;  B: col=lane&31, k=(lane>>5)*8+e
//   D: col=lane&31, row=(r&3)+8*(r>>2)+4*(lane>>5)
// K-slot packing: k0..3 {2x0h,2x0h,2x0l,2x0l}x{y0h,y0l,y0h,y0l} = 2*x0*y0;
// k4..7 dim1; k8..11 dim2; k12,13 {-xx_h,-xx_l}x{1,1}; k14,15 {1,1}x{-yy_h,-yy_l}
// => with C=0: D = 2x.y - xx - yy = -d2.  min d2 = -max D.

static __device__ inline void split_bf(float v, __bf16& h, __bf16& l) {
    h = (__bf16)v;
    l = (__bf16)(v - (float)h);
}

__global__ __launch_bounds__(BLK, 4) void chamfer_one(
    const float* __restrict__ y,     // v      [B, M, 3] targets
    const float* __restrict__ x,     // v_pred [B, N, 3] queries
    float* __restrict__ part,        // ws
    int*   __restrict__ group_cnt,
    float* __restrict__ total,
    int*   __restrict__ gcnt,
    const int* __restrict__ probe,
    float* __restrict__ out)
{
    __shared__ uint4 FR[NJT * 64];   // 32 KB; A image (8 KB) then B image
    __shared__ int   lastFlag;
    __shared__ float wsum[4];

    const int t   = threadIdx.x;
    const int l   = t & 63;
    const int w   = t >> 6;          // wave 0..3
    const int hi  = l >> 5;          // frag part
    const int c32 = l & 31;
    const int ib  = blockIdx.x;      // query chunk 0..31
    const int s   = blockIdx.y;      // target chunk 0..7
    const int b   = blockIdx.z;      // batch
    const int g   = b * (NN / QB) + ib;   // group 0..127

    const int P = *probe;            // uniform fill pattern (never written)

    // ---- stage A fragment image: 256 queries, 1 per thread ----
    {
        const float* xb = x + ((size_t)b * NN + (size_t)ib * QB) * 3;
        float x0 = xb[3*t+0], x1 = xb[3*t+1], x2 = xb[3*t+2];
        __bf16 h0,l0,h1,l1,h2,l2;
        split_bf(2.0f*x0, h0, l0);
        split_bf(2.0f*x1, h1, l1);
        split_bf(2.0f*x2, h2, l2);
        float nxx = -__builtin_fmaf(x2, x2, __builtin_fmaf(x1, x1, x0*x0));
        __bf16 hx, lx; split_bf(nxx, hx, lx);
        const __bf16 one = (__bf16)1.0f;
        bf16x8 g0 = {h0,h0,l0,l0,h1,h1,l1,l1};
        bf16x8 g1 = {h2,h2,l2,l2,hx,lx,one,one};
        const int at = t >> 5, col = t & 31;
        FR[at*64 +      col] = __builtin_bit_cast(uint4, g0);
        FR[at*64 + 32 + col] = __builtin_bit_cast(uint4, g1);
    }
    __syncthreads();
    const bf16x8 a0 = __builtin_bit_cast(bf16x8, FR[(w*2 + 0)*64 + l]);
    const bf16x8 a1 = __builtin_bit_cast(bf16x8, FR[(w*2 + 1)*64 + l]);
    __syncthreads();

    // ---- stage B fragment image: 1024 targets, 4 per thread ----
    {
        const float* yb = y + ((size_t)b * MM + (size_t)s * TC) * 3;
        const __bf16 one = (__bf16)1.0f;
#pragma unroll
        for (int k2 = 0; k2 < 4; ++k2) {
            const int j = t + k2 * BLK;
            float y0 = yb[3*j+0], y1 = yb[3*j+1], y2 = yb[3*j+2];
            __bf16 h0,l0,h1,l1,h2,l2;
            split_bf(y0, h0, l0);
            split_bf(y1, h1, l1);
            split_bf(y2, h2, l2);
            float nyy = -__builtin_fmaf(y2, y2, __builtin_fmaf(y1, y1, y0*y0));
            __bf16 hy, ly; split_bf(nyy, hy, ly);
            bf16x8 g0 = {h0,l0,h0,l0,h1,l1,h1,l1};
            bf16x8 g1 = {h2,l2,h2,l2,one,one,hy,ly};
            const int jt = j >> 5, col = j & 31;
            FR[jt*64 +      col] = __builtin_bit_cast(uint4, g0);
            FR[jt*64 + 32 + col] = __builtin_bit_cast(uint4, g1);
        }
    }
    __syncthreads();

    // ---- main loop: paired j-tiles, v_max3 fold (8 VALU per MFMA = floor) ----
    f32x16 z;
#pragma unroll
    for (int r = 0; r < 16; ++r) z[r] = 0.0f;
    f32x16 best0, best1;
#pragma unroll
    for (int r = 0; r < 16; ++r) { best0[r] = -3.4e38f; best1[r] = -3.4e38f; }

#pragma unroll 1
    for (int jt = 0; jt < NJT; jt += 2) {
        const bf16x8 bf0 = __builtin_bit_cast(bf16x8, FR[jt*64 + l]);
        const bf16x8 bf1 = __builtin_bit_cast(bf16x8, FR[jt*64 + 64 + l]);
        f32x16 p = __builtin_amdgcn_mfma_f32_32x32x16_bf16(a0, bf0, z, 0, 0, 0);
        f32x16 q = __builtin_amdgcn_mfma_f32_32x32x16_bf16(a0, bf1, z, 0, 0, 0);
#pragma unroll
        for (int r = 0; r < 16; ++r)
            best0[r] = fmaxf(fmaxf(best0[r], p[r]), q[r]);   // v_max3_f32
        p = __builtin_amdgcn_mfma_f32_32x32x16_bf16(a1, bf0, z, 0, 0, 0);
        q = __builtin_amdgcn_mfma_f32_32x32x16_bf16(a1, bf1, z, 0, 0, 0);
#pragma unroll
        for (int r = 0; r < 16; ++r)
            best1[r] = fmaxf(fmaxf(best1[r], p[r]), q[r]);
    }

    // ---- col-reduce (32 targets) and write per-query minima (agent scope) ----
    float* pslot = part + ((size_t)g * S + s) * QB;
#pragma unroll
    for (int ii = 0; ii < 2; ++ii) {
        const f32x16 bb = ii ? best1 : best0;
#pragma unroll
        for (int r = 0; r < 16; ++r) {
            float v = bb[r];
            v = fmaxf(v, __shfl_xor(v, 1, 64));
            v = fmaxf(v, __shfl_xor(v, 2, 64));
            v = fmaxf(v, __shfl_xor(v, 4, 64));
            v = fmaxf(v, __shfl_xor(v, 8, 64));
            v = fmaxf(v, __shfl_xor(v, 16, 64));
            if (c32 == 0) {
                const int qrow = (w*2 + ii)*32 + (r & 3) + 8*(r >> 2) + 4*hi;
                __hip_atomic_store(&pslot[qrow], -v, __ATOMIC_RELAXED,
                                   __HIP_MEMORY_SCOPE_AGENT);  // min d2 >= 0
            }
        }
    }

    __threadfence();                       // release before counter
    if (t == 0) {
        int old = atomicAdd(&group_cnt[g], 1);
        lastFlag = (old == P + S - 1);     // last of the 8 s-blocks
    }
    __syncthreads();
    if (!lastFlag) return;

    // ---- group finalize: min over 8 s-slices, sum 256 queries ----
    __threadfence();                       // acquire
    const float* pg = part + (size_t)g * S * QB;
    float dq = 3.4e38f;
#pragma unroll
    for (int ss = 0; ss < S; ++ss) {
        float vv = __hip_atomic_load(&pg[ss * QB + t], __ATOMIC_RELAXED,
                                     __HIP_MEMORY_SCOPE_AGENT);
        dq = fminf(dq, vv);
    }
    float acc = dq;
    for (int off = 32; off > 0; off >>= 1)
        acc += __shfl_down(acc, off, 64);
    if ((t & 63) == 0) wsum[t >> 6] = acc;
    __syncthreads();
    if (t == 0) {
        float Sg = wsum[0] + wsum[1] + wsum[2] + wsum[3];
        atomicAdd(total, Sg);              // base = poison float, ~ -3e-13
        __threadfence();
        int old2 = atomicAdd(gcnt, 1);
        if (old2 == P + NGRP - 1) {        // last group finalizes
            __threadfence();
            float tot = __hip_atomic_load(total, __ATOMIC_RELAXED,
                                          __HIP_MEMORY_SCOPE_AGENT);
            tot -= __int_as_float(P);      // remove poison bias exactly
            out[0] = tot * (1.0f / (float)BN);
        }
    }
}

extern "C" void kernel_launch(void* const* d_in, const int* in_sizes, int n_in,
                              void* d_out, int out_size, void* d_ws, size_t ws_size,
                              hipStream_t stream) {
    // setup_inputs order: d_in[0] = v (targets y), d_in[1] = v_pred (queries x)
    const float* v      = (const float*)d_in[0];
    const float* v_pred = (const float*)d_in[1];
    float* out = (float*)d_out;

    char* wsb = (char*)d_ws;
    float* part      = (float*)wsb;                        // 1 MB
    int*   group_cnt = (int*)(wsb + (1u << 20));           // 512 B
    float* total     = (float*)(wsb + (1u << 20) + 512);
    int*   gcnt      = (int*)(wsb + (1u << 20) + 516);
    int*   probe     = (int*)(wsb + (1u << 20) + 520);     // never written

    chamfer_one<<<dim3(NN / QB, S, BB), BLK, 0, stream>>>(
        v, v_pred, part, group_cnt, total, gcnt, probe, out);
}

// Round 6
// 73.442 us; speedup vs baseline: 1.8336x; 1.8336x over previous
//
#include <hip/hip_runtime.h>

// Problem constants: v (targets y), v_pred (queries x) are [4, 8192, 3] fp32.
#define BB 4
#define NN 8192
#define MM 8192
#define BN (BB * NN)

#define BLK 256        // threads per block = 4 waves
#define QB  256        // queries per block = 8 A-tiles of 32 (2 per wave)
#define TC  1024       // targets per s-chunk = 32 B-tiles (32 KB LDS image)
#define S   (MM / TC)  // 8 s-chunks = 8 blocks per (ib,b) group
#define NJT (TC / 32)  // 32 j-tiles per chunk
#define NGRP ((NN / QB) * BB)   // 128 groups
// grid (NN/QB, S, BB) = (32, 8, 4) = 1024 blocks = 4 blocks/CU, 16 waves/CU.

#define RB 32          // reduce_groups blocks
#define GPB (NGRP / RB) // 4 groups per reduce block

typedef __bf16 bf16x8 __attribute__((ext_vector_type(8)));
typedef float  f32x16 __attribute__((ext_vector_type(16)));

// ws layout (bytes):
//   [0, 1MB)        part: float[128 groups][8 s][256 q]  per-query per-s min d2
//   [1MB, 1MB+128)  ws2: float[32] reduce-block partials
// All ws reads happen strictly after a kernel boundary that wrote them
// (in-stream ordering) -> no fences, no atomics, no poison sensitivity.
//
// v_mfma_f32_32x32x16_bf16 (layouts verified by R0/R2/R5 absmax=0.0):
//   A: row=lane&31, k=(lane>>5)*8+e;  B: col=lane&31, k=(lane>>5)*8+e
//   D: col=lane&31, row=(r&3)+8*(r>>2)+4*(lane>>5)
// K-slot packing: k0..3 {2x0h,2x0h,2x0l,2x0l}x{y0h,y0l,y0h,y0l} = 2*x0*y0;
// k4..7 dim1; k8..11 dim2; k12,13 {-xx_h,-xx_l}x{1,1}; k14,15 {1,1}x{-yy_h,-yy_l}
// => with C=0: D = 2x.y - xx - yy = -d2.  min d2 = -max D.

static __device__ inline void split_bf(float v, __bf16& h, __bf16& l) {
    h = (__bf16)v;
    l = (__bf16)(v - (float)h);
}

__global__ __launch_bounds__(BLK, 4) void chamfer_part(
    const float* __restrict__ y,     // v      [B, M, 3] targets
    const float* __restrict__ x,     // v_pred [B, N, 3] queries
    float* __restrict__ part)        // ws [NGRP][S][QB]
{
    __shared__ uint4 FR[NJT * 64];   // 32 KB; A image (8 KB) then B image
    __shared__ float red[QB];        // per-query min for this (g, s)

    const int t   = threadIdx.x;
    const int l   = t & 63;
    const int w   = t >> 6;          // wave 0..3
    const int hi  = l >> 5;          // frag part
    const int c32 = l & 31;
    const int ib  = blockIdx.x;      // query chunk 0..31
    const int s   = blockIdx.y;      // target chunk 0..7
    const int b   = blockIdx.z;      // batch
    const int g   = b * (NN / QB) + ib;   // group 0..127

    // ---- stage A fragment image: 256 queries, 1 per thread ----
    {
        const float* xb = x + ((size_t)b * NN + (size_t)ib * QB) * 3;
        float x0 = xb[3*t+0], x1 = xb[3*t+1], x2 = xb[3*t+2];
        __bf16 h0,l0,h1,l1,h2,l2;
        split_bf(2.0f*x0, h0, l0);
        split_bf(2.0f*x1, h1, l1);
        split_bf(2.0f*x2, h2, l2);
        float nxx = -__builtin_fmaf(x2, x2, __builtin_fmaf(x1, x1, x0*x0));
        __bf16 hx, lx; split_bf(nxx, hx, lx);
        const __bf16 one = (__bf16)1.0f;
        bf16x8 g0 = {h0,h0,l0,l0,h1,h1,l1,l1};
        bf16x8 g1 = {h2,h2,l2,l2,hx,lx,one,one};
        const int at = t >> 5, col = t & 31;
        FR[at*64 +      col] = __builtin_bit_cast(uint4, g0);
        FR[at*64 + 32 + col] = __builtin_bit_cast(uint4, g1);
    }
    __syncthreads();
    const bf16x8 a0 = __builtin_bit_cast(bf16x8, FR[(w*2 + 0)*64 + l]);
    const bf16x8 a1 = __builtin_bit_cast(bf16x8, FR[(w*2 + 1)*64 + l]);
    __syncthreads();

    // ---- stage B fragment image: 1024 targets, 4 per thread ----
    {
        const float* yb = y + ((size_t)b * MM + (size_t)s * TC) * 3;
        const __bf16 one = (__bf16)1.0f;
#pragma unroll
        for (int k2 = 0; k2 < 4; ++k2) {
            const int j = t + k2 * BLK;
            float y0 = yb[3*j+0], y1 = yb[3*j+1], y2 = yb[3*j+2];
            __bf16 h0,l0,h1,l1,h2,l2;
            split_bf(y0, h0, l0);
            split_bf(y1, h1, l1);
            split_bf(y2, h2, l2);
            float nyy = -__builtin_fmaf(y2, y2, __builtin_fmaf(y1, y1, y0*y0));
            __bf16 hy, ly; split_bf(nyy, hy, ly);
            bf16x8 g0 = {h0,l0,h0,l0,h1,l1,h1,l1};
            bf16x8 g1 = {h2,l2,h2,l2,one,one,hy,ly};
            const int jt = j >> 5, col = j & 31;
            FR[jt*64 +      col] = __builtin_bit_cast(uint4, g0);
            FR[jt*64 + 32 + col] = __builtin_bit_cast(uint4, g1);
        }
    }
    __syncthreads();

    // ---- main loop: paired j-tiles, v_max3 fold ----
    f32x16 z;
#pragma unroll
    for (int r = 0; r < 16; ++r) z[r] = 0.0f;
    f32x16 best0, best1;
#pragma unroll
    for (int r = 0; r < 16; ++r) { best0[r] = -3.4e38f; best1[r] = -3.4e38f; }

#pragma unroll 1
    for (int jt = 0; jt < NJT; jt += 2) {
        const bf16x8 bf0 = __builtin_bit_cast(bf16x8, FR[jt*64 + l]);
        const bf16x8 bf1 = __builtin_bit_cast(bf16x8, FR[jt*64 + 64 + l]);
        f32x16 p = __builtin_amdgcn_mfma_f32_32x32x16_bf16(a0, bf0, z, 0, 0, 0);
        f32x16 q = __builtin_amdgcn_mfma_f32_32x32x16_bf16(a0, bf1, z, 0, 0, 0);
#pragma unroll
        for (int r = 0; r < 16; ++r)
            best0[r] = fmaxf(fmaxf(best0[r], p[r]), q[r]);   // v_max3_f32
        p = __builtin_amdgcn_mfma_f32_32x32x16_bf16(a1, bf0, z, 0, 0, 0);
        q = __builtin_amdgcn_mfma_f32_32x32x16_bf16(a1, bf1, z, 0, 0, 0);
#pragma unroll
        for (int r = 0; r < 16; ++r)
            best1[r] = fmaxf(fmaxf(best1[r], p[r]), q[r]);
    }

    // ---- col-reduce (32 targets) into LDS, then ONE coalesced store ----
#pragma unroll
    for (int ii = 0; ii < 2; ++ii) {
        const f32x16 bb = ii ? best1 : best0;
#pragma unroll
        for (int r = 0; r < 16; ++r) {
            float v = bb[r];
            v = fmaxf(v, __shfl_xor(v, 1, 64));
            v = fmaxf(v, __shfl_xor(v, 2, 64));
            v = fmaxf(v, __shfl_xor(v, 4, 64));
            v = fmaxf(v, __shfl_xor(v, 8, 64));
            v = fmaxf(v, __shfl_xor(v, 16, 64));
            if (c32 == 0) {
                const int qrow = (w*2 + ii)*32 + (r & 3) + 8*(r >> 2) + 4*hi;
                red[qrow] = -v;                 // min d2 for this (g, s, q)
            }
        }
    }
    __syncthreads();
    part[((size_t)g * S + s) * QB + t] = red[t];  // plain coalesced store
}

// Kernel 2: 32 blocks x 256 thr; each block: 4 groups -> one partial sum.
__global__ __launch_bounds__(BLK) void reduce_groups(
    const float* __restrict__ part,   // [NGRP][S][QB]
    float* __restrict__ ws2)          // [RB]
{
    const int t = threadIdx.x;
    float acc = 0.0f;
#pragma unroll
    for (int gi = 0; gi < GPB; ++gi) {
        const float* pg = part + ((size_t)(blockIdx.x * GPB + gi) * S) * QB;
        float dq = pg[t];
#pragma unroll
        for (int ss = 1; ss < S; ++ss)
            dq = fminf(dq, pg[ss * QB + t]);
        acc += dq;
    }
    // block sum: wave shfl + LDS
    for (int off = 32; off > 0; off >>= 1)
        acc += __shfl_down(acc, off, 64);
    __shared__ float wsum[4];
    if ((t & 63) == 0) wsum[t >> 6] = acc;
    __syncthreads();
    if (t == 0)
        ws2[blockIdx.x] = wsum[0] + wsum[1] + wsum[2] + wsum[3];
}

// Kernel 3: one wave sums the 32 partials.
__global__ __launch_bounds__(64) void final32(
    const float* __restrict__ ws2,    // [RB]
    float* __restrict__ out)
{
    const int t = threadIdx.x;
    float v = (t < RB) ? ws2[t] : 0.0f;
    for (int off = 32; off > 0; off >>= 1)
        v += __shfl_down(v, off, 64);
    if (t == 0) out[0] = v * (1.0f / (float)BN);
}

extern "C" void kernel_launch(void* const* d_in, const int* in_sizes, int n_in,
                              void* d_out, int out_size, void* d_ws, size_t ws_size,
                              hipStream_t stream) {
    // setup_inputs order: d_in[0] = v (targets y), d_in[1] = v_pred (queries x)
    const float* v      = (const float*)d_in[0];
    const float* v_pred = (const float*)d_in[1];
    float* out = (float*)d_out;

    float* part = (float*)d_ws;                         // 1 MB
    float* ws2  = (float*)((char*)d_ws + (1u << 20));   // 128 B

    chamfer_part<<<dim3(NN / QB, S, BB), BLK, 0, stream>>>(v, v_pred, part);
    reduce_groups<<<RB, BLK, 0, stream>>>(part, ws2);
    final32<<<1, 64, 0, stream>>>(ws2, out);
}